// Round 3
// baseline (155.099 us; speedup 1.0000x reference)
//
#include <hip/hip_runtime.h>
#include <stdint.h>

#define S_LEN 2048
#define BATCH 2
#define DMODEL 1024
#define NHEAD 16
#define DK 64
#define MROWS (BATCH * S_LEN) /* 4096 */

typedef __attribute__((ext_vector_type(8))) short bf16x8;
typedef __attribute__((ext_vector_type(4))) float f32x4;
typedef __attribute__((ext_vector_type(4))) short short4v;

__device__ __forceinline__ short f2b(float f) {
    union { float f; uint32_t u; } c; c.f = f;
    uint32_t u = c.u;
    return (short)((u + 0x7fffu + ((u >> 16) & 1u)) >> 16);
}

__device__ __forceinline__ void gload16(const void* g, void* l) {
    __builtin_amdgcn_global_load_lds(
        (const __attribute__((address_space(1))) void*)g,
        (__attribute__((address_space(3))) void*)l, 16, 0, 0);
}

// ---------------------------------------------------------------- fp32 -> bf16
__global__ void cvt_kernel(const float* __restrict__ X, const float* __restrict__ Wq,
                           const float* __restrict__ Wk, const float* __restrict__ Wv,
                           const float* __restrict__ Wo,
                           short* __restrict__ Xb, short* __restrict__ Wqb,
                           short* __restrict__ Wkb, short* __restrict__ Wvb,
                           short* __restrict__ Wob) {
    const float* src; short* dst; int n4;
    switch (blockIdx.y) {
        case 0:  src = X;  dst = Xb;  n4 = MROWS * DMODEL / 4;  break;
        case 1:  src = Wq; dst = Wqb; n4 = DMODEL * DMODEL / 4; break;
        case 2:  src = Wk; dst = Wkb; n4 = DMODEL * DMODEL / 4; break;
        case 3:  src = Wv; dst = Wvb; n4 = DMODEL * DMODEL / 4; break;
        default: src = Wo; dst = Wob; n4 = DMODEL * DMODEL / 4; break;
    }
    for (int i = blockIdx.x * blockDim.x + threadIdx.x; i < n4;
         i += gridDim.x * blockDim.x) {
        float4 v = ((const float4*)src)[i];
        short4v o;
        o[0] = f2b(v.x); o[1] = f2b(v.y); o[2] = f2b(v.z); o[3] = f2b(v.w);
        ((short4v*)dst)[i] = o;
    }
}

// ------------------------------------------------- C = A * Bt^T  (bf16 MFMA)
// A [M,K] bf16 row-major, Bt [N,K] bf16 row-major (nn.Linear weight layout).
// 128x128 tile, BK=32, 4 waves (2x2), each wave 64x64 (4x4 of 16x16x32 MFMA).
template <int OUT_F32>
__global__ __launch_bounds__(256) void gemm_bt(
    const short* __restrict__ A,
    const short* __restrict__ Bt0, const short* __restrict__ Bt1,
    const short* __restrict__ Bt2,
    short* __restrict__ Cb0, short* __restrict__ Cb1, short* __restrict__ Cb2,
    float* __restrict__ Cf, int M, int N, int K) {
    __shared__ short sA[128 * 32];
    __shared__ short sB[128 * 32];

    const short* Bt = Bt0;
    short* Cb = Cb0;
    if (blockIdx.z == 1) { Bt = Bt1; Cb = Cb1; }
    else if (blockIdx.z == 2) { Bt = Bt2; Cb = Cb2; }

    const int tid = threadIdx.x;
    const int lane = tid & 63;
    const int wid = tid >> 6;
    const int wr = wid >> 1, wc = wid & 1;
    const int brow = blockIdx.y * 128;
    const int bcol = blockIdx.x * 128;
    const int lr = lane & 15;
    const int kh = (lane >> 4) << 3;

    f32x4 acc[4][4] = {};

    const int idx0 = tid, idx1 = tid + 256;
    const int ar0 = idx0 >> 2, ak0 = (idx0 & 3) << 3;
    const int ar1 = idx1 >> 2, ak1 = (idx1 & 3) << 3;

    const int nk = K >> 5;
    for (int kt = 0; kt < nk; ++kt) {
        __syncthreads();
        const int k0 = kt << 5;
        gload16(A + (size_t)(brow + ar0) * K + k0 + ak0, &sA[idx0 * 8]);
        gload16(A + (size_t)(brow + ar1) * K + k0 + ak1, &sA[idx1 * 8]);
        gload16(Bt + (size_t)(bcol + ar0) * K + k0 + ak0, &sB[idx0 * 8]);
        gload16(Bt + (size_t)(bcol + ar1) * K + k0 + ak1, &sB[idx1 * 8]);
        __syncthreads();

        bf16x8 a[4], b[4];
#pragma unroll
        for (int mt = 0; mt < 4; ++mt)
            a[mt] = *(const bf16x8*)&sA[(wr * 64 + mt * 16 + lr) * 32 + kh];
#pragma unroll
        for (int nt = 0; nt < 4; ++nt)
            b[nt] = *(const bf16x8*)&sB[(wc * 64 + nt * 16 + lr) * 32 + kh];
#pragma unroll
        for (int mt = 0; mt < 4; ++mt)
#pragma unroll
            for (int nt = 0; nt < 4; ++nt)
                acc[mt][nt] = __builtin_amdgcn_mfma_f32_16x16x32_bf16(
                    a[mt], b[nt], acc[mt][nt], 0, 0, 0);
    }

    const int rbase = (lane >> 4) << 2;
#pragma unroll
    for (int mt = 0; mt < 4; ++mt) {
#pragma unroll
        for (int nt = 0; nt < 4; ++nt) {
#pragma unroll
            for (int j = 0; j < 4; ++j) {
                int row = brow + wr * 64 + mt * 16 + rbase + j;
                int col = bcol + wc * 64 + nt * 16 + lr;
                if (OUT_F32)
                    Cf[(size_t)row * N + col] = acc[mt][nt][j];
                else
                    Cb[(size_t)row * N + col] = f2b(acc[mt][nt][j]);
            }
        }
    }
}

// ------------------------------------------------------------- flash attention
// Q,K,V,O: [4096,1024] bf16, head h = cols h*64..h*64+63, batch b = rows b*2048..
// Block: 256 thr (4 waves); wave w handles 16 q-rows. Key tiles of 64.
__global__ __launch_bounds__(256) void attn_kernel(
    const short* __restrict__ Q, const short* __restrict__ K,
    const short* __restrict__ V, short* __restrict__ O,
    const int* __restrict__ vlens) {
    __shared__ short sK[64 * 64];
    __shared__ short sVt[64 * 72];  // [d][key], pad 8 keeps 16B alignment
    __shared__ short sP[4][16 * 64];

    const int tid = threadIdx.x;
    const int lane = tid & 63;
    const int w = tid >> 6;
    const int bh = blockIdx.y;
    const int b = bh >> 4, h = bh & 15;
    const int qb = blockIdx.x;
    const int lr = lane & 15;
    const int kh = (lane >> 4) << 3;
    const int rbase = (lane >> 4) << 2;

    int vl = vlens[b];
    if (vl < 0) vl = 0;
    if (vl > S_LEN) vl = S_LEN;
    const bool allm = (vl == 0);
    const int nT = allm ? (S_LEN / 64) : ((vl + 63) >> 6);

    const size_t rowbase = (size_t)(b * S_LEN) * DMODEL + h * DK;

    const short* qrow = Q + rowbase + (size_t)(qb * 64 + w * 16 + lr) * DMODEL;
    bf16x8 qf0 = *(const bf16x8*)(qrow + kh);
    bf16x8 qf1 = *(const bf16x8*)(qrow + 32 + kh);

    f32x4 oac[4] = {};
    float m[4], l[4];
#pragma unroll
    for (int j = 0; j < 4; ++j) { m[j] = -1e30f; l[j] = 0.f; }

    const int sr0 = tid >> 3, ss0 = (tid & 7) << 3;
    const int idx1 = tid + 256;
    const int sr1 = idx1 >> 3, ss1 = (idx1 & 7) << 3;

    for (int t = 0; t < nT; ++t) {
        __syncthreads();
        const short* kbase = K + rowbase + (size_t)(t * 64) * DMODEL;
        gload16(kbase + (size_t)sr0 * DMODEL + ss0, &sK[tid * 8]);
        gload16(kbase + (size_t)sr1 * DMODEL + ss1, &sK[idx1 * 8]);
        const short* vbase = V + rowbase + (size_t)(t * 64) * DMODEL;
        bf16x8 v0 = *(const bf16x8*)(vbase + (size_t)sr0 * DMODEL + ss0);
        bf16x8 v1 = *(const bf16x8*)(vbase + (size_t)sr1 * DMODEL + ss1);
#pragma unroll
        for (int j2 = 0; j2 < 8; ++j2) sVt[(ss0 + j2) * 72 + sr0] = v0[j2];
#pragma unroll
        for (int j2 = 0; j2 < 8; ++j2) sVt[(ss1 + j2) * 72 + sr1] = v1[j2];
        __syncthreads();

        // QK^T scores: 4 col-tiles x (dk=64 -> 2 MFMA)
        f32x4 sacc[4] = {};
#pragma unroll
        for (int nt = 0; nt < 4; ++nt) {
            bf16x8 kb0 = *(const bf16x8*)&sK[(nt * 16 + lr) * 64 + kh];
            bf16x8 kb1 = *(const bf16x8*)&sK[(nt * 16 + lr) * 64 + 32 + kh];
            sacc[nt] = __builtin_amdgcn_mfma_f32_16x16x32_bf16(qf0, kb0, sacc[nt], 0, 0, 0);
            sacc[nt] = __builtin_amdgcn_mfma_f32_16x16x32_bf16(qf1, kb1, sacc[nt], 0, 0, 0);
        }

        float s[4][4];
        bool msk[4];
#pragma unroll
        for (int nt = 0; nt < 4; ++nt) {
            int key = t * 64 + nt * 16 + lr;
            msk[nt] = (!allm) && (key >= vl);
#pragma unroll
            for (int j = 0; j < 4; ++j)
                s[nt][j] = allm ? 0.f : (msk[nt] ? -1e30f : sacc[nt][j] * 0.125f);
        }

        float pv[4][4], scl[4];
#pragma unroll
        for (int j = 0; j < 4; ++j) {
            float mx = fmaxf(fmaxf(s[0][j], s[1][j]), fmaxf(s[2][j], s[3][j]));
#pragma unroll
            for (int off = 1; off < 16; off <<= 1)
                mx = fmaxf(mx, __shfl_xor(mx, off));
            float mnew = fmaxf(m[j], mx);
            scl[j] = __expf(m[j] - mnew);
            float ls = 0.f;
#pragma unroll
            for (int nt = 0; nt < 4; ++nt) {
                float p = msk[nt] ? 0.f : __expf(s[nt][j] - mnew);
                pv[nt][j] = p;
                ls += p;
            }
#pragma unroll
            for (int off = 1; off < 16; off <<= 1)
                ls += __shfl_xor(ls, off);
            l[j] = l[j] * scl[j] + ls;
            m[j] = mnew;
        }
#pragma unroll
        for (int dt = 0; dt < 4; ++dt)
#pragma unroll
            for (int j = 0; j < 4; ++j)
                oac[dt][j] *= scl[j];

#pragma unroll
        for (int nt = 0; nt < 4; ++nt)
#pragma unroll
            for (int j = 0; j < 4; ++j)
                sP[w][(rbase + j) * 64 + nt * 16 + lr] = f2b(pv[nt][j]);

#pragma unroll
        for (int ks = 0; ks < 2; ++ks) {
            bf16x8 pf = *(const bf16x8*)&sP[w][lr * 64 + ks * 32 + kh];
#pragma unroll
            for (int dt = 0; dt < 4; ++dt) {
                bf16x8 vf = *(const bf16x8*)&sVt[(dt * 16 + lr) * 72 + ks * 32 + kh];
                oac[dt] = __builtin_amdgcn_mfma_f32_16x16x32_bf16(pf, vf, oac[dt], 0, 0, 0);
            }
        }
    }

#pragma unroll
    for (int dt = 0; dt < 4; ++dt) {
#pragma unroll
        for (int j = 0; j < 4; ++j) {
            int q = qb * 64 + w * 16 + rbase + j;
            float inv = 1.f / l[j];
            O[rowbase + (size_t)q * DMODEL + dt * 16 + lr] = f2b(oac[dt][j] * inv);
        }
    }
}

extern "C" void kernel_launch(void* const* d_in, const int* in_sizes, int n_in,
                              void* d_out, int out_size, void* d_ws, size_t ws_size,
                              hipStream_t stream) {
    const float* X = (const float*)d_in[0];
    const int* vlens = (const int*)d_in[1];
    const float* Wq = (const float*)d_in[2];
    const float* Wk = (const float*)d_in[3];
    const float* Wv = (const float*)d_in[4];
    const float* Wo = (const float*)d_in[5];
    float* out = (float*)d_out;

    short* Xb = (short*)d_ws;
    short* Wqb = Xb + (size_t)MROWS * DMODEL;
    short* Wkb = Wqb + (size_t)DMODEL * DMODEL;
    short* Wvb = Wkb + (size_t)DMODEL * DMODEL;
    short* Wob = Wvb + (size_t)DMODEL * DMODEL;
    short* Qb = Wob + (size_t)DMODEL * DMODEL;
    short* Kb = Qb + (size_t)MROWS * DMODEL;
    short* Vb = Kb + (size_t)MROWS * DMODEL;
    short* Ob = Vb + (size_t)MROWS * DMODEL;

    cvt_kernel<<<dim3(512, 5), 256, 0, stream>>>(X, Wq, Wk, Wv, Wo, Xb, Wqb, Wkb,
                                                 Wvb, Wob);
    gemm_bt<0><<<dim3(8, 32, 3), 256, 0, stream>>>(Xb, Wqb, Wkb, Wvb, Qb, Kb, Vb,
                                                   nullptr, MROWS, DMODEL, DMODEL);
    attn_kernel<<<dim3(32, 32), 256, 0, stream>>>(Qb, Kb, Vb, Ob, vlens);
    gemm_bt<1><<<dim3(8, 32, 1), 256, 0, stream>>>(Ob, Wob, Wob, Wob, nullptr,
                                                   nullptr, nullptr, out, MROWS,
                                                   DMODEL, DMODEL);
}

// Round 4
// 138.743 us; speedup vs baseline: 1.1179x; 1.1179x over previous
//
#include <hip/hip_runtime.h>
#include <stdint.h>

#define S_LEN 2048
#define BATCH 2
#define DMODEL 1024
#define NHEAD 16
#define DK 64
#define MROWS (BATCH * S_LEN) /* 4096 */

typedef __attribute__((ext_vector_type(8))) short bf16x8;
typedef __attribute__((ext_vector_type(4))) float f32x4;
typedef __attribute__((ext_vector_type(4))) short short4v;

__device__ __forceinline__ short f2b(float f) {
    union { float f; uint32_t u; } c; c.f = f;
    uint32_t u = c.u;
    return (short)((u + 0x7fffu + ((u >> 16) & 1u)) >> 16);
}

__device__ __forceinline__ void gload16(const void* g, void* l) {
    __builtin_amdgcn_global_load_lds(
        (const __attribute__((address_space(1))) void*)g,
        (__attribute__((address_space(3))) void*)l, 16, 0, 0);
}

// ---------------------------------------------------------------- fp32 -> bf16
__global__ void cvt_kernel(const float* __restrict__ X, const float* __restrict__ Wq,
                           const float* __restrict__ Wk, const float* __restrict__ Wv,
                           const float* __restrict__ Wo,
                           short* __restrict__ Xb, short* __restrict__ Wqb,
                           short* __restrict__ Wkb, short* __restrict__ Wvb,
                           short* __restrict__ Wob) {
    const float* src; short* dst; int n4;
    switch (blockIdx.y) {
        case 0:  src = X;  dst = Xb;  n4 = MROWS * DMODEL / 4;  break;
        case 1:  src = Wq; dst = Wqb; n4 = DMODEL * DMODEL / 4; break;
        case 2:  src = Wk; dst = Wkb; n4 = DMODEL * DMODEL / 4; break;
        case 3:  src = Wv; dst = Wvb; n4 = DMODEL * DMODEL / 4; break;
        default: src = Wo; dst = Wob; n4 = DMODEL * DMODEL / 4; break;
    }
    for (int i = blockIdx.x * blockDim.x + threadIdx.x; i < n4;
         i += gridDim.x * blockDim.x) {
        float4 v = ((const float4*)src)[i];
        short4v o;
        o[0] = f2b(v.x); o[1] = f2b(v.y); o[2] = f2b(v.z); o[3] = f2b(v.w);
        ((short4v*)dst)[i] = o;
    }
}

// ------------------------------------------------- C = A * Bt^T  (bf16 MFMA)
template <int OUT_F32>
__global__ __launch_bounds__(256) void gemm_bt(
    const short* __restrict__ A,
    const short* __restrict__ Bt0, const short* __restrict__ Bt1,
    const short* __restrict__ Bt2,
    short* __restrict__ Cb0, short* __restrict__ Cb1, short* __restrict__ Cb2,
    float* __restrict__ Cf, int M, int N, int K) {
    __shared__ short sA[128 * 32];
    __shared__ short sB[128 * 32];

    const short* Bt = Bt0;
    short* Cb = Cb0;
    if (blockIdx.z == 1) { Bt = Bt1; Cb = Cb1; }
    else if (blockIdx.z == 2) { Bt = Bt2; Cb = Cb2; }

    const int tid = threadIdx.x;
    const int lane = tid & 63;
    const int wid = tid >> 6;
    const int wr = wid >> 1, wc = wid & 1;
    const int brow = blockIdx.y * 128;
    const int bcol = blockIdx.x * 128;
    const int lr = lane & 15;
    const int kh = (lane >> 4) << 3;

    f32x4 acc[4][4] = {};

    const int idx0 = tid, idx1 = tid + 256;
    const int ar0 = idx0 >> 2, ak0 = (idx0 & 3) << 3;
    const int ar1 = idx1 >> 2, ak1 = (idx1 & 3) << 3;

    const int nk = K >> 5;
    for (int kt = 0; kt < nk; ++kt) {
        __syncthreads();
        const int k0 = kt << 5;
        gload16(A + (size_t)(brow + ar0) * K + k0 + ak0, &sA[idx0 * 8]);
        gload16(A + (size_t)(brow + ar1) * K + k0 + ak1, &sA[idx1 * 8]);
        gload16(Bt + (size_t)(bcol + ar0) * K + k0 + ak0, &sB[idx0 * 8]);
        gload16(Bt + (size_t)(bcol + ar1) * K + k0 + ak1, &sB[idx1 * 8]);
        __syncthreads();

        bf16x8 a[4], b[4];
#pragma unroll
        for (int mt = 0; mt < 4; ++mt)
            a[mt] = *(const bf16x8*)&sA[(wr * 64 + mt * 16 + lr) * 32 + kh];
#pragma unroll
        for (int nt = 0; nt < 4; ++nt)
            b[nt] = *(const bf16x8*)&sB[(wc * 64 + nt * 16 + lr) * 32 + kh];
#pragma unroll
        for (int mt = 0; mt < 4; ++mt)
#pragma unroll
            for (int nt = 0; nt < 4; ++nt)
                acc[mt][nt] = __builtin_amdgcn_mfma_f32_16x16x32_bf16(
                    a[mt], b[nt], acc[mt][nt], 0, 0, 0);
    }

    const int rbase = (lane >> 4) << 2;
#pragma unroll
    for (int mt = 0; mt < 4; ++mt) {
#pragma unroll
        for (int nt = 0; nt < 4; ++nt) {
#pragma unroll
            for (int j = 0; j < 4; ++j) {
                int row = brow + wr * 64 + mt * 16 + rbase + j;
                int col = bcol + wc * 64 + nt * 16 + lr;
                if (OUT_F32)
                    Cf[(size_t)row * N + col] = acc[mt][nt][j];
                else
                    Cb[(size_t)row * N + col] = f2b(acc[mt][nt][j]);
            }
        }
    }
}

// ------------------------------------------------------------- flash attention
// Q,K,V,O: [4096,1024] bf16. Block: 256 thr / 4 waves; wave = 16 q-rows.
// sK swizzle: shortidx = r*64 + (c ^ ((r&7)<<3))         (both-sides, rule 21)
// sVt swizzle: shortidx = d*64 + (k ^ ((((d&7)^((d>>3)&7)))<<3))
// sP swizzle:  shortidx = r*64 + (c ^ ((r&7)<<3))   (per-wave private)
__global__ __launch_bounds__(256) void attn_kernel(
    const short* __restrict__ Q, const short* __restrict__ K,
    const short* __restrict__ V, short* __restrict__ O,
    const int* __restrict__ vlens) {
    __shared__ short sK[2][64 * 64];
    __shared__ short sVt[2][64 * 64];
    __shared__ short sP[4][16 * 64];

    const int tid = threadIdx.x;
    const int lane = tid & 63;
    const int w = tid >> 6;
    const int bh = blockIdx.y;
    const int b = bh >> 4, h = bh & 15;
    const int qb = blockIdx.x;
    const int lr = lane & 15;
    const int kh = (lane >> 4) << 3;
    const int rbase = (lane >> 4) << 2;

    int vl = vlens[b];
    if (vl < 0) vl = 0;
    if (vl > S_LEN) vl = S_LEN;
    const bool allm = (vl == 0);
    const int nT = allm ? (S_LEN / 64) : ((vl + 63) >> 6);

    const size_t rowbase = (size_t)(b * S_LEN) * DMODEL + h * DK;

    const short* qrow = Q + rowbase + (size_t)(qb * 64 + w * 16 + lr) * DMODEL;
    bf16x8 qf0 = *(const bf16x8*)(qrow + kh);
    bf16x8 qf1 = *(const bf16x8*)(qrow + 32 + kh);

    f32x4 oac[4] = {};
    float m[4], l[4];
#pragma unroll
    for (int j = 0; j < 4; ++j) { m[j] = -1e30f; l[j] = 0.f; }

    // K staging geometry (512 16B chunks): chunk ci -> row ci>>3, pre-swizzled col
    const int kr0 = tid >> 3;                  // chunk0 row
    const int kr1 = kr0 + 32;                  // chunk1 row
    const int kc0 = (((tid & 7) ^ (kr0 & 7)) << 3);
    const int kc1 = (((tid & 7) ^ (kr1 & 7)) << 3);
    // V staging geometry: chunk ci -> key row, 8 d-elems
    const int sr0 = tid >> 3, ss0 = (tid & 7) << 3;
    const int sr1 = sr0 + 32, ss1 = ss0;

    // ---- prologue: stage tile 0 into buffer 0
    {
        const short* kbase = K + rowbase;
        gload16(kbase + (size_t)kr0 * DMODEL + kc0, &sK[0][tid * 8]);
        gload16(kbase + (size_t)kr1 * DMODEL + kc1, &sK[0][(tid + 256) * 8]);
        const short* vbase = V + rowbase;
        bf16x8 v0 = *(const bf16x8*)(vbase + (size_t)sr0 * DMODEL + ss0);
        bf16x8 v1 = *(const bf16x8*)(vbase + (size_t)sr1 * DMODEL + ss1);
#pragma unroll
        for (int j2 = 0; j2 < 8; ++j2) {
            int d = ss0 + j2;
            int key = (((d & 7) ^ ((d >> 3) & 7)) << 3);
            sVt[0][d * 64 + (sr0 ^ key)] = v0[j2];
            sVt[0][d * 64 + (sr1 ^ key)] = v1[j2];
        }
    }
    __syncthreads();

    int cur = 0;
    for (int t = 0; t < nT; ++t) {
        const bool hn = (t + 1 < nT);
        short* sKn = sK[cur ^ 1];
        short* sVtn = sVt[cur ^ 1];
        const short* sKc = sK[cur];
        const short* sVtc = sVt[cur];

        bf16x8 v0n, v1n;
        if (hn) {
            const short* kbase = K + rowbase + (size_t)((t + 1) * 64) * DMODEL;
            gload16(kbase + (size_t)kr0 * DMODEL + kc0, &sKn[tid * 8]);
            gload16(kbase + (size_t)kr1 * DMODEL + kc1, &sKn[(tid + 256) * 8]);
            const short* vbase = V + rowbase + (size_t)((t + 1) * 64) * DMODEL;
            v0n = *(const bf16x8*)(vbase + (size_t)sr0 * DMODEL + ss0);
            v1n = *(const bf16x8*)(vbase + (size_t)sr1 * DMODEL + ss1);
        }

        // QK^T scores: 4 col-tiles x (dk=64 -> 2 MFMA)
        f32x4 sacc[4] = {};
#pragma unroll
        for (int nt = 0; nt < 4; ++nt) {
            int R = nt * 16 + lr;
            int sw = (R & 7) << 3;
            bf16x8 kb0 = *(const bf16x8*)&sKc[R * 64 + (kh ^ sw)];
            bf16x8 kb1 = *(const bf16x8*)&sKc[R * 64 + ((32 + kh) ^ sw)];
            sacc[nt] = __builtin_amdgcn_mfma_f32_16x16x32_bf16(qf0, kb0, sacc[nt], 0, 0, 0);
            sacc[nt] = __builtin_amdgcn_mfma_f32_16x16x32_bf16(qf1, kb1, sacc[nt], 0, 0, 0);
        }

        float s[4][4];
        bool msk[4];
#pragma unroll
        for (int nt = 0; nt < 4; ++nt) {
            int keyi = t * 64 + nt * 16 + lr;
            msk[nt] = (!allm) && (keyi >= vl);
#pragma unroll
            for (int j = 0; j < 4; ++j)
                s[nt][j] = allm ? 0.f : (msk[nt] ? -1e30f : sacc[nt][j] * 0.125f);
        }

        float pv[4][4], scl[4];
#pragma unroll
        for (int j = 0; j < 4; ++j) {
            float mx = fmaxf(fmaxf(s[0][j], s[1][j]), fmaxf(s[2][j], s[3][j]));
#pragma unroll
            for (int off = 1; off < 16; off <<= 1)
                mx = fmaxf(mx, __shfl_xor(mx, off));
            float mnew = fmaxf(m[j], mx);
            scl[j] = __expf(m[j] - mnew);
            float ls = 0.f;
#pragma unroll
            for (int nt = 0; nt < 4; ++nt) {
                float p = msk[nt] ? 0.f : __expf(s[nt][j] - mnew);
                pv[nt][j] = p;
                ls += p;
            }
#pragma unroll
            for (int off = 1; off < 16; off <<= 1)
                ls += __shfl_xor(ls, off);
            l[j] = l[j] * scl[j] + ls;
            m[j] = mnew;
        }
#pragma unroll
        for (int dt = 0; dt < 4; ++dt)
#pragma unroll
            for (int j = 0; j < 4; ++j)
                oac[dt][j] *= scl[j];

#pragma unroll
        for (int nt = 0; nt < 4; ++nt)
#pragma unroll
            for (int j = 0; j < 4; ++j) {
                int row = rbase + j;
                int sw = (row & 7) << 3;
                sP[w][row * 64 + ((nt * 16 + lr) ^ sw)] = f2b(pv[nt][j]);
            }

#pragma unroll
        for (int ks = 0; ks < 2; ++ks) {
            int swp = (lr & 7) << 3;
            bf16x8 pf = *(const bf16x8*)&sP[w][lr * 64 + ((ks * 32 + kh) ^ swp)];
#pragma unroll
            for (int dt = 0; dt < 4; ++dt) {
                int drow = dt * 16 + lr;
                int keyv = (((drow & 7) ^ ((drow >> 3) & 7)) << 3);
                bf16x8 vf = *(const bf16x8*)&sVtc[drow * 64 + ((ks * 32 + kh) ^ keyv)];
                oac[dt] = __builtin_amdgcn_mfma_f32_16x16x32_bf16(pf, vf, oac[dt], 0, 0, 0);
            }
        }

        if (hn) {
#pragma unroll
            for (int j2 = 0; j2 < 8; ++j2) {
                int d = ss0 + j2;
                int key = (((d & 7) ^ ((d >> 3) & 7)) << 3);
                sVtn[d * 64 + (sr0 ^ key)] = v0n[j2];
                sVtn[d * 64 + (sr1 ^ key)] = v1n[j2];
            }
        }
        __syncthreads();
        cur ^= 1;
    }

#pragma unroll
    for (int dt = 0; dt < 4; ++dt) {
#pragma unroll
        for (int j = 0; j < 4; ++j) {
            int q = qb * 64 + w * 16 + rbase + j;
            float inv = 1.f / l[j];
            O[rowbase + (size_t)q * DMODEL + dt * 16 + lr] = f2b(oac[dt][j] * inv);
        }
    }
}

extern "C" void kernel_launch(void* const* d_in, const int* in_sizes, int n_in,
                              void* d_out, int out_size, void* d_ws, size_t ws_size,
                              hipStream_t stream) {
    const float* X = (const float*)d_in[0];
    const int* vlens = (const int*)d_in[1];
    const float* Wq = (const float*)d_in[2];
    const float* Wk = (const float*)d_in[3];
    const float* Wv = (const float*)d_in[4];
    const float* Wo = (const float*)d_in[5];
    float* out = (float*)d_out;

    short* Xb = (short*)d_ws;
    short* Wqb = Xb + (size_t)MROWS * DMODEL;
    short* Wkb = Wqb + (size_t)DMODEL * DMODEL;
    short* Wvb = Wkb + (size_t)DMODEL * DMODEL;
    short* Wob = Wvb + (size_t)DMODEL * DMODEL;
    short* Qb = Wob + (size_t)DMODEL * DMODEL;
    short* Kb = Qb + (size_t)MROWS * DMODEL;
    short* Vb = Kb + (size_t)MROWS * DMODEL;
    short* Ob = Vb + (size_t)MROWS * DMODEL;

    cvt_kernel<<<dim3(512, 5), 256, 0, stream>>>(X, Wq, Wk, Wv, Wo, Xb, Wqb, Wkb,
                                                 Wvb, Wob);
    gemm_bt<0><<<dim3(8, 32, 3), 256, 0, stream>>>(Xb, Wqb, Wkb, Wvb, Qb, Kb, Vb,
                                                   nullptr, MROWS, DMODEL, DMODEL);
    attn_kernel<<<dim3(32, 32), 256, 0, stream>>>(Qb, Kb, Vb, Ob, vlens);
    gemm_bt<1><<<dim3(8, 32, 1), 256, 0, stream>>>(Ob, Wob, Wob, Wob, nullptr,
                                                   nullptr, nullptr, out, MROWS,
                                                   DMODEL, DMODEL);
}

// Round 5
// 129.403 us; speedup vs baseline: 1.1986x; 1.0722x over previous
//
#include <hip/hip_runtime.h>
#include <stdint.h>

#define S_LEN 2048
#define BATCH 2
#define DMODEL 1024
#define NHEAD 16
#define DK 64
#define MROWS (BATCH * S_LEN) /* 4096 */

typedef __attribute__((ext_vector_type(8))) short bf16x8;
typedef __attribute__((ext_vector_type(4))) float f32x4;
typedef __attribute__((ext_vector_type(4))) short short4v;

__device__ __forceinline__ short f2b(float f) {
    union { float f; uint32_t u; } c; c.f = f;
    uint32_t u = c.u;
    return (short)((u + 0x7fffu + ((u >> 16) & 1u)) >> 16);
}

__device__ __forceinline__ void gload16(const void* g, void* l) {
    __builtin_amdgcn_global_load_lds(
        (const __attribute__((address_space(1))) void*)g,
        (__attribute__((address_space(3))) void*)l, 16, 0, 0);
}

// ---------------------------------------------------------------- fp32 -> bf16
__global__ void cvt_kernel(const float* __restrict__ X, const float* __restrict__ Wq,
                           const float* __restrict__ Wk, const float* __restrict__ Wv,
                           const float* __restrict__ Wo,
                           short* __restrict__ Xb, short* __restrict__ Wqb,
                           short* __restrict__ Wkb, short* __restrict__ Wvb,
                           short* __restrict__ Wob) {
    const float* src; short* dst; int n4;
    switch (blockIdx.y) {
        case 0:  src = X;  dst = Xb;  n4 = MROWS * DMODEL / 4;  break;
        case 1:  src = Wq; dst = Wqb; n4 = DMODEL * DMODEL / 4; break;
        case 2:  src = Wk; dst = Wkb; n4 = DMODEL * DMODEL / 4; break;
        case 3:  src = Wv; dst = Wvb; n4 = DMODEL * DMODEL / 4; break;
        default: src = Wo; dst = Wob; n4 = DMODEL * DMODEL / 4; break;
    }
    for (int i = blockIdx.x * blockDim.x + threadIdx.x; i < n4;
         i += gridDim.x * blockDim.x) {
        float4 v = ((const float4*)src)[i];
        short4v o;
        o[0] = f2b(v.x); o[1] = f2b(v.y); o[2] = f2b(v.z); o[3] = f2b(v.w);
        ((short4v*)dst)[i] = o;
    }
}

// ------------------------------------------------- C = A * Bt^T  (bf16 MFMA)
template <int OUT_F32>
__global__ __launch_bounds__(256) void gemm_bt(
    const short* __restrict__ A,
    const short* __restrict__ Bt0, const short* __restrict__ Bt1,
    const short* __restrict__ Bt2,
    short* __restrict__ Cb0, short* __restrict__ Cb1, short* __restrict__ Cb2,
    float* __restrict__ Cf, int M, int N, int K) {
    __shared__ short sA[128 * 32];
    __shared__ short sB[128 * 32];

    const short* Bt = Bt0;
    short* Cb = Cb0;
    if (blockIdx.z == 1) { Bt = Bt1; Cb = Cb1; }
    else if (blockIdx.z == 2) { Bt = Bt2; Cb = Cb2; }

    const int tid = threadIdx.x;
    const int lane = tid & 63;
    const int wid = tid >> 6;
    const int wr = wid >> 1, wc = wid & 1;
    const int brow = blockIdx.y * 128;
    const int bcol = blockIdx.x * 128;
    const int lr = lane & 15;
    const int kh = (lane >> 4) << 3;

    f32x4 acc[4][4] = {};

    const int idx0 = tid, idx1 = tid + 256;
    const int ar0 = idx0 >> 2, ak0 = (idx0 & 3) << 3;
    const int ar1 = idx1 >> 2, ak1 = (idx1 & 3) << 3;

    const int nk = K >> 5;
    for (int kt = 0; kt < nk; ++kt) {
        __syncthreads();
        const int k0 = kt << 5;
        gload16(A + (size_t)(brow + ar0) * K + k0 + ak0, &sA[idx0 * 8]);
        gload16(A + (size_t)(brow + ar1) * K + k0 + ak1, &sA[idx1 * 8]);
        gload16(Bt + (size_t)(bcol + ar0) * K + k0 + ak0, &sB[idx0 * 8]);
        gload16(Bt + (size_t)(bcol + ar1) * K + k0 + ak1, &sB[idx1 * 8]);
        __syncthreads();

        bf16x8 a[4], b[4];
#pragma unroll
        for (int mt = 0; mt < 4; ++mt)
            a[mt] = *(const bf16x8*)&sA[(wr * 64 + mt * 16 + lr) * 32 + kh];
#pragma unroll
        for (int nt = 0; nt < 4; ++nt)
            b[nt] = *(const bf16x8*)&sB[(wc * 64 + nt * 16 + lr) * 32 + kh];
#pragma unroll
        for (int mt = 0; mt < 4; ++mt)
#pragma unroll
            for (int nt = 0; nt < 4; ++nt)
                acc[mt][nt] = __builtin_amdgcn_mfma_f32_16x16x32_bf16(
                    a[mt], b[nt], acc[mt][nt], 0, 0, 0);
    }

    const int rbase = (lane >> 4) << 2;
#pragma unroll
    for (int mt = 0; mt < 4; ++mt) {
#pragma unroll
        for (int nt = 0; nt < 4; ++nt) {
#pragma unroll
            for (int j = 0; j < 4; ++j) {
                int row = brow + wr * 64 + mt * 16 + rbase + j;
                int col = bcol + wc * 64 + nt * 16 + lr;
                if (OUT_F32)
                    Cf[(size_t)row * N + col] = acc[mt][nt][j];
                else
                    Cb[(size_t)row * N + col] = f2b(acc[mt][nt][j]);
            }
        }
    }
}

// ------------------------------------------------------------- flash attention
// Swapped QK^T: sacc = mfma(K_frag, Q_frag) -> S^T[key][q].
// Lane owns query q = lane&15; its 16 scores sit in registers
// (key = nt*16 + (lane>>4)*4 + j). Softmax: 15 local + 2 shfl_xor.
// PV unchanged orientation: oac rows q=(lane>>4)*4+j -> scale factors shfl'd.
__global__ __launch_bounds__(256) void attn_kernel(
    const short* __restrict__ Q, const short* __restrict__ K,
    const short* __restrict__ V, short* __restrict__ O,
    const int* __restrict__ vlens) {
    __shared__ short sK[2][64 * 64];
    __shared__ short sVt[2][64 * 64];
    __shared__ short sP[4][16 * 64];

    const int tid = threadIdx.x;
    const int lane = tid & 63;
    const int w = tid >> 6;
    const int bh = blockIdx.y;
    const int b = bh >> 4, h = bh & 15;
    const int qb = blockIdx.x;
    const int lr = lane & 15;
    const int kh = (lane >> 4) << 3;
    const int rbase = (lane >> 4) << 2;
    const int swq = (lr & 7) << 3;

    int vl = vlens[b];
    if (vl < 0) vl = 0;
    if (vl > S_LEN) vl = S_LEN;
    const bool allm = (vl == 0);
    if (allm) vl = S_LEN;  // qf=0 -> scores 0 -> uniform softmax == reference
    const int nT = (vl + 63) >> 6;
    const int nFull = ((vl & 63) == 0) ? nT : nT - 1;

    const size_t rowbase = (size_t)(b * S_LEN) * DMODEL + h * DK;

    const short* qrow = Q + rowbase + (size_t)(qb * 64 + w * 16 + lr) * DMODEL;
    bf16x8 qf0 = *(const bf16x8*)(qrow + kh);
    bf16x8 qf1 = *(const bf16x8*)(qrow + 32 + kh);
    if (allm) {
#pragma unroll
        for (int i = 0; i < 8; ++i) { qf0[i] = 0; qf1[i] = 0; }
    }

    f32x4 oac[4] = {};
    float m_run = -1e30f, l_run = 0.f;
    const float CEXP = 0.18033688011112042f;  // 0.125 * log2(e)

    // K staging geometry (pre-swizzled global source, linear LDS dest)
    const int kr0 = tid >> 3;
    const int kr1 = kr0 + 32;
    const int kc0 = (((tid & 7) ^ (kr0 & 7)) << 3);
    const int kc1 = (((tid & 7) ^ (kr1 & 7)) << 3);
    // V staging geometry
    const int sr0 = tid >> 3, ss0 = (tid & 7) << 3;
    const int sr1 = sr0 + 32;

    uint32_t* sPw = (uint32_t*)&sP[w][0];

    // ---- prologue: stage tile 0 into buffer 0
    {
        const short* kbase = K + rowbase;
        gload16(kbase + (size_t)kr0 * DMODEL + kc0, &sK[0][tid * 8]);
        gload16(kbase + (size_t)kr1 * DMODEL + kc1, &sK[0][(tid + 256) * 8]);
        const short* vbase = V + rowbase;
        bf16x8 v0 = *(const bf16x8*)(vbase + (size_t)sr0 * DMODEL + ss0);
        bf16x8 v1 = *(const bf16x8*)(vbase + (size_t)sr1 * DMODEL + ss0);
#pragma unroll
        for (int j2 = 0; j2 < 8; ++j2) {
            int d = ss0 + j2;
            int key = (((d & 7) ^ ((d >> 3) & 7)) << 3);
            sVt[0][d * 64 + (sr0 ^ key)] = v0[j2];
            sVt[0][d * 64 + (sr1 ^ key)] = v1[j2];
        }
    }
    __syncthreads();

#define TILE_BODY(MASKED_C)                                                     \
    do {                                                                        \
        constexpr bool MASKED = MASKED_C;                                       \
        const short* sKc = sK[cur];                                             \
        const short* sVtc = sVt[cur];                                           \
        f32x4 sacc[4] = {};                                                     \
        __builtin_amdgcn_s_setprio(1);                                          \
        _Pragma("unroll")                                                       \
        for (int nt = 0; nt < 4; ++nt) {                                        \
            int R = nt * 16 + lr;                                               \
            int sw = (R & 7) << 3;                                              \
            bf16x8 kb0 = *(const bf16x8*)&sKc[R * 64 + (kh ^ sw)];              \
            bf16x8 kb1 = *(const bf16x8*)&sKc[R * 64 + ((32 + kh) ^ sw)];       \
            sacc[nt] = __builtin_amdgcn_mfma_f32_16x16x32_bf16(                 \
                kb0, qf0, sacc[nt], 0, 0, 0);                                   \
            sacc[nt] = __builtin_amdgcn_mfma_f32_16x16x32_bf16(                 \
                kb1, qf1, sacc[nt], 0, 0, 0);                                   \
        }                                                                       \
        __builtin_amdgcn_s_setprio(0);                                          \
        float s[16];                                                            \
        _Pragma("unroll")                                                       \
        for (int nt = 0; nt < 4; ++nt)                                          \
            _Pragma("unroll")                                                   \
            for (int j = 0; j < 4; ++j) {                                       \
                float v = sacc[nt][j];                                          \
                if (MASKED) {                                                   \
                    int keyi = t * 64 + nt * 16 + rbase + j;                    \
                    if (keyi >= vl) v = -3.0e38f;                               \
                }                                                               \
                s[nt * 4 + j] = v;                                              \
            }                                                                   \
        float mx01 = fmaxf(fmaxf(s[0], s[1]), fmaxf(s[2], s[3]));               \
        float mx23 = fmaxf(fmaxf(s[4], s[5]), fmaxf(s[6], s[7]));               \
        float mx45 = fmaxf(fmaxf(s[8], s[9]), fmaxf(s[10], s[11]));             \
        float mx67 = fmaxf(fmaxf(s[12], s[13]), fmaxf(s[14], s[15]));           \
        float mx = fmaxf(fmaxf(mx01, mx23), fmaxf(mx45, mx67));                 \
        mx = fmaxf(mx, __shfl_xor(mx, 16));                                     \
        mx = fmaxf(mx, __shfl_xor(mx, 32));                                     \
        float mnew = fmaxf(m_run, mx);                                          \
        float mc = mnew * CEXP;                                                 \
        float scl = __builtin_exp2f(m_run * CEXP - mc);                         \
        float p[16];                                                            \
        _Pragma("unroll")                                                       \
        for (int i = 0; i < 16; ++i)                                            \
            p[i] = __builtin_exp2f(s[i] * CEXP - mc);                           \
        float ls = ((p[0] + p[1]) + (p[2] + p[3])) +                            \
                   ((p[4] + p[5]) + (p[6] + p[7]));                             \
        ls += ((p[8] + p[9]) + (p[10] + p[11])) +                               \
              ((p[12] + p[13]) + (p[14] + p[15]));                              \
        ls += __shfl_xor(ls, 16);                                               \
        ls += __shfl_xor(ls, 32);                                               \
        l_run = l_run * scl + ls;                                               \
        m_run = mnew;                                                           \
        _Pragma("unroll")                                                       \
        for (int nt = 0; nt < 4; ++nt)                                          \
            _Pragma("unroll")                                                   \
            for (int pi = 0; pi < 2; ++pi) {                                    \
                uint32_t r;                                                     \
                asm("v_cvt_pk_bf16_f32 %0, %1, %2"                              \
                    : "=v"(r)                                                   \
                    : "v"(p[nt * 4 + 2 * pi]), "v"(p[nt * 4 + 2 * pi + 1]));    \
                int key0 = nt * 16 + rbase + 2 * pi;                            \
                sPw[(lr * 64 + (key0 ^ swq)) >> 1] = r;                         \
            }                                                                   \
        float sclq[4];                                                          \
        _Pragma("unroll")                                                       \
        for (int j = 0; j < 4; ++j) sclq[j] = __shfl(scl, rbase + j);           \
        _Pragma("unroll")                                                       \
        for (int dt = 0; dt < 4; ++dt)                                          \
            _Pragma("unroll")                                                   \
            for (int j = 0; j < 4; ++j) oac[dt][j] *= sclq[j];                  \
        __builtin_amdgcn_s_setprio(1);                                          \
        _Pragma("unroll")                                                       \
        for (int ks = 0; ks < 2; ++ks) {                                        \
            bf16x8 pf = *(const bf16x8*)&sP[w][lr * 64 + ((ks * 32 + kh) ^ swq)]; \
            _Pragma("unroll")                                                   \
            for (int dt = 0; dt < 4; ++dt) {                                    \
                int drow = dt * 16 + lr;                                        \
                int keyv = (((drow & 7) ^ ((drow >> 3) & 7)) << 3);             \
                bf16x8 vf = *(const bf16x8*)&sVtc[drow * 64 +                   \
                                                  ((ks * 32 + kh) ^ keyv)];     \
                oac[dt] = __builtin_amdgcn_mfma_f32_16x16x32_bf16(              \
                    pf, vf, oac[dt], 0, 0, 0);                                  \
            }                                                                   \
        }                                                                       \
        __builtin_amdgcn_s_setprio(0);                                          \
    } while (0)

    int cur = 0;
    for (int t = 0; t < nT; ++t) {
        const bool hn = (t + 1 < nT);
        short* sKn = sK[cur ^ 1];
        short* sVtn = sVt[cur ^ 1];

        bf16x8 v0n, v1n;
        if (hn) {
            const short* kbase = K + rowbase + (size_t)((t + 1) * 64) * DMODEL;
            gload16(kbase + (size_t)kr0 * DMODEL + kc0, &sKn[tid * 8]);
            gload16(kbase + (size_t)kr1 * DMODEL + kc1, &sKn[(tid + 256) * 8]);
            const short* vbase = V + rowbase + (size_t)((t + 1) * 64) * DMODEL;
            v0n = *(const bf16x8*)(vbase + (size_t)sr0 * DMODEL + ss0);
            v1n = *(const bf16x8*)(vbase + (size_t)sr1 * DMODEL + ss0);
        }

        if (t < nFull) TILE_BODY(false);
        else TILE_BODY(true);

        if (hn) {
#pragma unroll
            for (int j2 = 0; j2 < 8; ++j2) {
                int d = ss0 + j2;
                int key = (((d & 7) ^ ((d >> 3) & 7)) << 3);
                sVtn[d * 64 + (sr0 ^ key)] = v0n[j2];
                sVtn[d * 64 + (sr1 ^ key)] = v1n[j2];
            }
        }
        __syncthreads();
        cur ^= 1;
    }
#undef TILE_BODY

    float rl = 1.f / l_run;
    float rlq[4];
#pragma unroll
    for (int j = 0; j < 4; ++j) rlq[j] = __shfl(rl, rbase + j);
#pragma unroll
    for (int dt = 0; dt < 4; ++dt) {
#pragma unroll
        for (int j = 0; j < 4; ++j) {
            int q = qb * 64 + w * 16 + rbase + j;
            O[rowbase + (size_t)q * DMODEL + dt * 16 + lr] = f2b(oac[dt][j] * rlq[j]);
        }
    }
}

extern "C" void kernel_launch(void* const* d_in, const int* in_sizes, int n_in,
                              void* d_out, int out_size, void* d_ws, size_t ws_size,
                              hipStream_t stream) {
    const float* X = (const float*)d_in[0];
    const int* vlens = (const int*)d_in[1];
    const float* Wq = (const float*)d_in[2];
    const float* Wk = (const float*)d_in[3];
    const float* Wv = (const float*)d_in[4];
    const float* Wo = (const float*)d_in[5];
    float* out = (float*)d_out;

    short* Xb = (short*)d_ws;
    short* Wqb = Xb + (size_t)MROWS * DMODEL;
    short* Wkb = Wqb + (size_t)DMODEL * DMODEL;
    short* Wvb = Wkb + (size_t)DMODEL * DMODEL;
    short* Wob = Wvb + (size_t)DMODEL * DMODEL;
    short* Qb = Wob + (size_t)DMODEL * DMODEL;
    short* Kb = Qb + (size_t)MROWS * DMODEL;
    short* Vb = Kb + (size_t)MROWS * DMODEL;
    short* Ob = Vb + (size_t)MROWS * DMODEL;

    cvt_kernel<<<dim3(512, 5), 256, 0, stream>>>(X, Wq, Wk, Wv, Wo, Xb, Wqb, Wkb,
                                                 Wvb, Wob);
    gemm_bt<0><<<dim3(8, 32, 3), 256, 0, stream>>>(Xb, Wqb, Wkb, Wvb, Qb, Kb, Vb,
                                                   nullptr, MROWS, DMODEL, DMODEL);
    attn_kernel<<<dim3(32, 32), 256, 0, stream>>>(Qb, Kb, Vb, Ob, vlens);
    gemm_bt<1><<<dim3(8, 32, 1), 256, 0, stream>>>(Ob, Wob, Wob, Wob, nullptr,
                                                   nullptr, nullptr, out, MROWS,
                                                   DMODEL, DMODEL);
}

// Round 6
// 117.839 us; speedup vs baseline: 1.3162x; 1.0981x over previous
//
#include <hip/hip_runtime.h>
#include <stdint.h>

#define S_LEN 2048
#define BATCH 2
#define DMODEL 1024
#define NHEAD 16
#define DK 64
#define MROWS (BATCH * S_LEN) /* 4096 */

typedef __attribute__((ext_vector_type(8))) short bf16x8;
typedef __attribute__((ext_vector_type(4))) float f32x4;
typedef __attribute__((ext_vector_type(4))) short short4v;

__device__ __forceinline__ short f2b(float f) {
    union { float f; uint32_t u; } c; c.f = f;
    uint32_t u = c.u;
    return (short)((u + 0x7fffu + ((u >> 16) & 1u)) >> 16);
}

__device__ __forceinline__ void gload16(const void* g, void* l) {
    __builtin_amdgcn_global_load_lds(
        (const __attribute__((address_space(1))) void*)g,
        (__attribute__((address_space(3))) void*)l, 16, 0, 0);
}

// ---------------------------------------------------------------- fp32 -> bf16
__global__ void cvt_kernel(const float* __restrict__ X, const float* __restrict__ Wq,
                           const float* __restrict__ Wk, const float* __restrict__ Wv,
                           const float* __restrict__ Wo,
                           short* __restrict__ Xb, short* __restrict__ Wqb,
                           short* __restrict__ Wkb, short* __restrict__ Wvb,
                           short* __restrict__ Wob) {
    const float* src; short* dst; int n4;
    switch (blockIdx.y) {
        case 0:  src = X;  dst = Xb;  n4 = MROWS * DMODEL / 4;  break;
        case 1:  src = Wq; dst = Wqb; n4 = DMODEL * DMODEL / 4; break;
        case 2:  src = Wk; dst = Wkb; n4 = DMODEL * DMODEL / 4; break;
        case 3:  src = Wv; dst = Wvb; n4 = DMODEL * DMODEL / 4; break;
        default: src = Wo; dst = Wob; n4 = DMODEL * DMODEL / 4; break;
    }
    for (int i = blockIdx.x * blockDim.x + threadIdx.x; i < n4;
         i += gridDim.x * blockDim.x) {
        float4 v = ((const float4*)src)[i];
        short4v o;
        o[0] = f2b(v.x); o[1] = f2b(v.y); o[2] = f2b(v.z); o[3] = f2b(v.w);
        ((short4v*)dst)[i] = o;
    }
}

// ------------------------------------------------- C = A * Bt^T  (bf16 MFMA)
// z==2 (V) writes TRANSPOSED per-head: Vt[b][h][d][key], packed 4xbf16 stores.
template <int OUT_F32>
__global__ __launch_bounds__(256) void gemm_bt(
    const short* __restrict__ A,
    const short* __restrict__ Bt0, const short* __restrict__ Bt1,
    const short* __restrict__ Bt2,
    short* __restrict__ Cb0, short* __restrict__ Cb1, short* __restrict__ Cb2,
    float* __restrict__ Cf, int M, int N, int K) {
    __shared__ short sA[128 * 32];
    __shared__ short sB[128 * 32];

    const short* Bt = Bt0;
    short* Cb = Cb0;
    if (blockIdx.z == 1) { Bt = Bt1; Cb = Cb1; }
    else if (blockIdx.z == 2) { Bt = Bt2; Cb = Cb2; }

    const int tid = threadIdx.x;
    const int lane = tid & 63;
    const int wid = tid >> 6;
    const int wr = wid >> 1, wc = wid & 1;
    const int brow = blockIdx.y * 128;
    const int bcol = blockIdx.x * 128;
    const int lr = lane & 15;
    const int kh = (lane >> 4) << 3;

    f32x4 acc[4][4] = {};

    const int idx0 = tid, idx1 = tid + 256;
    const int ar0 = idx0 >> 2, ak0 = (idx0 & 3) << 3;
    const int ar1 = idx1 >> 2, ak1 = (idx1 & 3) << 3;

    const int nk = K >> 5;
    for (int kt = 0; kt < nk; ++kt) {
        __syncthreads();
        const int k0 = kt << 5;
        gload16(A + (size_t)(brow + ar0) * K + k0 + ak0, &sA[idx0 * 8]);
        gload16(A + (size_t)(brow + ar1) * K + k0 + ak1, &sA[idx1 * 8]);
        gload16(Bt + (size_t)(bcol + ar0) * K + k0 + ak0, &sB[idx0 * 8]);
        gload16(Bt + (size_t)(bcol + ar1) * K + k0 + ak1, &sB[idx1 * 8]);
        __syncthreads();

        bf16x8 a[4], b[4];
#pragma unroll
        for (int mt = 0; mt < 4; ++mt)
            a[mt] = *(const bf16x8*)&sA[(wr * 64 + mt * 16 + lr) * 32 + kh];
#pragma unroll
        for (int nt = 0; nt < 4; ++nt)
            b[nt] = *(const bf16x8*)&sB[(wc * 64 + nt * 16 + lr) * 32 + kh];
#pragma unroll
        for (int mt = 0; mt < 4; ++mt)
#pragma unroll
            for (int nt = 0; nt < 4; ++nt)
                acc[mt][nt] = __builtin_amdgcn_mfma_f32_16x16x32_bf16(
                    a[mt], b[nt], acc[mt][nt], 0, 0, 0);
    }

    const int rbase = (lane >> 4) << 2;
    const bool vtrans = (!OUT_F32) && (blockIdx.z == 2);
#pragma unroll
    for (int mt = 0; mt < 4; ++mt) {
#pragma unroll
        for (int nt = 0; nt < 4; ++nt) {
            if (vtrans) {
                int row0 = brow + wr * 64 + mt * 16 + rbase;  // key (4 consecutive)
                int col = bcol + wc * 64 + nt * 16 + lr;
                int bb = row0 >> 11, key = row0 & 2047;
                int hh = col >> 6, d = col & 63;
                short4v pk;
#pragma unroll
                for (int j = 0; j < 4; ++j) pk[j] = f2b(acc[mt][nt][j]);
                *(short4v*)&Cb[((size_t)((bb * 16 + hh) * 64 + d)) * S_LEN + key] = pk;
            } else {
#pragma unroll
                for (int j = 0; j < 4; ++j) {
                    int row = brow + wr * 64 + mt * 16 + rbase + j;
                    int col = bcol + wc * 64 + nt * 16 + lr;
                    if (OUT_F32)
                        Cf[(size_t)row * N + col] = acc[mt][nt][j];
                    else
                        Cb[(size_t)row * N + col] = f2b(acc[mt][nt][j]);
                }
            }
        }
    }
}

// ------------------------------------------------------------- flash attention
// Swapped QK^T (lane owns q=lane&15, 16 key-scores in regs). K and Vt both
// staged linearly via global_load_lds with pre-swizzled SOURCE columns; reads
// use the matching XOR (both-sides involution). Vt is pre-transposed by the
// V-GEMM epilogue: Vt[b][h][d][key], so no per-tile transpose VALU work.
__global__ __launch_bounds__(256) void attn_kernel(
    const short* __restrict__ Q, const short* __restrict__ K,
    const short* __restrict__ Vt, short* __restrict__ O,
    const int* __restrict__ vlens) {
    __shared__ short sK[2][64 * 64];
    __shared__ short sV[2][64 * 64];
    __shared__ short sP[4][16 * 64];

    const int tid = threadIdx.x;
    const int lane = tid & 63;
    const int w = tid >> 6;
    // XCD-chunked bijective swizzle (1024 = 8 XCD * 128), batch-interleaved bh
    const int id = blockIdx.x;
    const int id2 = ((id & 7) << 7) | (id >> 3);
    const int qb = id2 & 31;
    const int bhx = id2 >> 5;
    const int b = bhx & 1, h = bhx >> 1;
    const int lr = lane & 15;
    const int kh = (lane >> 4) << 3;
    const int rbase = (lane >> 4) << 2;
    const int swq = (lr & 7) << 3;

    int vl = vlens[b];
    if (vl < 0) vl = 0;
    if (vl > S_LEN) vl = S_LEN;
    const bool allm = (vl == 0);
    if (allm) vl = S_LEN;  // qf=0 -> scores 0 -> uniform softmax == reference
    const int nT = (vl + 63) >> 6;
    const int nFull = ((vl & 63) == 0) ? nT : nT - 1;

    const size_t rowbase = (size_t)(b * S_LEN) * DMODEL + h * DK;
    const short* vt = Vt + ((size_t)((b * 16 + h) * 64)) * S_LEN;

    const short* qrow = Q + rowbase + (size_t)(qb * 64 + w * 16 + lr) * DMODEL;
    bf16x8 qf0 = *(const bf16x8*)(qrow + kh);
    bf16x8 qf1 = *(const bf16x8*)(qrow + 32 + kh);
    if (allm) {
#pragma unroll
        for (int i = 0; i < 8; ++i) { qf0[i] = 0; qf1[i] = 0; }
    }

    f32x4 oac[4] = {};
    float m_run = -1e30f, l_run = 0.f;
    const float CEXP = 0.18033688011112042f;  // 0.125 * log2(e)

    // staging geometry (pre-swizzled global source, linear LDS dest)
    const int kr0 = tid >> 3;
    const int kr1 = kr0 + 32;
    const int kc0 = (((tid & 7) ^ (kr0 & 7)) << 3);
    const int kc1 = (((tid & 7) ^ (kr1 & 7)) << 3);

    uint32_t* sPw = (uint32_t*)&sP[w][0];

    // ---- prologue: stage tile 0 into buffer 0
    {
        const short* kbase = K + rowbase;
        gload16(kbase + (size_t)kr0 * DMODEL + kc0, &sK[0][tid * 8]);
        gload16(kbase + (size_t)kr1 * DMODEL + kc1, &sK[0][(tid + 256) * 8]);
        gload16(vt + (size_t)kr0 * S_LEN + kc0, &sV[0][tid * 8]);
        gload16(vt + (size_t)kr1 * S_LEN + kc1, &sV[0][(tid + 256) * 8]);
    }
    __syncthreads();

#define TILE_BODY(MASKED_C)                                                     \
    do {                                                                        \
        constexpr bool MASKED = MASKED_C;                                       \
        const short* sKc = sK[cur];                                             \
        const short* sVc = sV[cur];                                             \
        f32x4 sacc[4] = {};                                                     \
        __builtin_amdgcn_s_setprio(1);                                          \
        _Pragma("unroll")                                                       \
        for (int nt = 0; nt < 4; ++nt) {                                        \
            int R = nt * 16 + lr;                                               \
            int sw = (R & 7) << 3;                                              \
            bf16x8 kb0 = *(const bf16x8*)&sKc[R * 64 + (kh ^ sw)];              \
            bf16x8 kb1 = *(const bf16x8*)&sKc[R * 64 + ((32 + kh) ^ sw)];       \
            sacc[nt] = __builtin_amdgcn_mfma_f32_16x16x32_bf16(                 \
                kb0, qf0, sacc[nt], 0, 0, 0);                                   \
            sacc[nt] = __builtin_amdgcn_mfma_f32_16x16x32_bf16(                 \
                kb1, qf1, sacc[nt], 0, 0, 0);                                   \
        }                                                                       \
        __builtin_amdgcn_s_setprio(0);                                          \
        float s[16];                                                            \
        _Pragma("unroll")                                                       \
        for (int nt = 0; nt < 4; ++nt)                                          \
            _Pragma("unroll")                                                   \
            for (int j = 0; j < 4; ++j) {                                       \
                float v = sacc[nt][j];                                          \
                if (MASKED) {                                                   \
                    int keyi = t * 64 + nt * 16 + rbase + j;                    \
                    if (keyi >= vl) v = -3.0e38f;                               \
                }                                                               \
                s[nt * 4 + j] = v;                                              \
            }                                                                   \
        float mx01 = fmaxf(fmaxf(s[0], s[1]), fmaxf(s[2], s[3]));               \
        float mx23 = fmaxf(fmaxf(s[4], s[5]), fmaxf(s[6], s[7]));               \
        float mx45 = fmaxf(fmaxf(s[8], s[9]), fmaxf(s[10], s[11]));             \
        float mx67 = fmaxf(fmaxf(s[12], s[13]), fmaxf(s[14], s[15]));           \
        float mx = fmaxf(fmaxf(mx01, mx23), fmaxf(mx45, mx67));                 \
        mx = fmaxf(mx, __shfl_xor(mx, 16));                                     \
        mx = fmaxf(mx, __shfl_xor(mx, 32));                                     \
        float mnew = fmaxf(m_run, mx);                                          \
        float mc = mnew * CEXP;                                                 \
        float scl = __builtin_exp2f(m_run * CEXP - mc);                         \
        float p[16];                                                            \
        _Pragma("unroll")                                                       \
        for (int i = 0; i < 16; ++i)                                            \
            p[i] = __builtin_exp2f(s[i] * CEXP - mc);                           \
        float ls = ((p[0] + p[1]) + (p[2] + p[3])) +                            \
                   ((p[4] + p[5]) + (p[6] + p[7]));                             \
        ls += ((p[8] + p[9]) + (p[10] + p[11])) +                               \
              ((p[12] + p[13]) + (p[14] + p[15]));                              \
        ls += __shfl_xor(ls, 16);                                               \
        ls += __shfl_xor(ls, 32);                                               \
        l_run = l_run * scl + ls;                                               \
        m_run = mnew;                                                           \
        _Pragma("unroll")                                                       \
        for (int nt = 0; nt < 4; ++nt)                                          \
            _Pragma("unroll")                                                   \
            for (int pi = 0; pi < 2; ++pi) {                                    \
                uint32_t r;                                                     \
                asm("v_cvt_pk_bf16_f32 %0, %1, %2"                              \
                    : "=v"(r)                                                   \
                    : "v"(p[nt * 4 + 2 * pi]), "v"(p[nt * 4 + 2 * pi + 1]));    \
                int key0 = nt * 16 + rbase + 2 * pi;                            \
                sPw[(lr * 64 + (key0 ^ swq)) >> 1] = r;                         \
            }                                                                   \
        float sclq[4];                                                          \
        _Pragma("unroll")                                                       \
        for (int j = 0; j < 4; ++j) sclq[j] = __shfl(scl, rbase + j);           \
        _Pragma("unroll")                                                       \
        for (int dt = 0; dt < 4; ++dt)                                          \
            _Pragma("unroll")                                                   \
            for (int j = 0; j < 4; ++j) oac[dt][j] *= sclq[j];                  \
        __builtin_amdgcn_s_setprio(1);                                          \
        _Pragma("unroll")                                                       \
        for (int ks = 0; ks < 2; ++ks) {                                        \
            bf16x8 pf = *(const bf16x8*)&sP[w][lr * 64 + ((ks * 32 + kh) ^ swq)]; \
            _Pragma("unroll")                                                   \
            for (int dt = 0; dt < 4; ++dt) {                                    \
                int drow = dt * 16 + lr;                                        \
                int swv = (drow & 7) << 3;                                      \
                bf16x8 vf = *(const bf16x8*)&sVc[drow * 64 +                    \
                                                 ((ks * 32 + kh) ^ swv)];       \
                oac[dt] = __builtin_amdgcn_mfma_f32_16x16x32_bf16(              \
                    pf, vf, oac[dt], 0, 0, 0);                                  \
            }                                                                   \
        }                                                                       \
        __builtin_amdgcn_s_setprio(0);                                          \
    } while (0)

    int cur = 0;
    for (int t = 0; t < nT; ++t) {
        const bool hn = (t + 1 < nT);
        if (hn) {
            short* sKn = sK[cur ^ 1];
            short* sVn = sV[cur ^ 1];
            const short* kbase = K + rowbase + (size_t)((t + 1) * 64) * DMODEL;
            gload16(kbase + (size_t)kr0 * DMODEL + kc0, &sKn[tid * 8]);
            gload16(kbase + (size_t)kr1 * DMODEL + kc1, &sKn[(tid + 256) * 8]);
            const short* vbase = vt + (t + 1) * 64;
            gload16(vbase + (size_t)kr0 * S_LEN + kc0, &sVn[tid * 8]);
            gload16(vbase + (size_t)kr1 * S_LEN + kc1, &sVn[(tid + 256) * 8]);
        }

        if (t < nFull) TILE_BODY(false);
        else TILE_BODY(true);

        __syncthreads();
        cur ^= 1;
    }
#undef TILE_BODY

    float rl = 1.f / l_run;
    float rlq[4];
#pragma unroll
    for (int j = 0; j < 4; ++j) rlq[j] = __shfl(rl, rbase + j);
#pragma unroll
    for (int dt = 0; dt < 4; ++dt) {
#pragma unroll
        for (int j = 0; j < 4; ++j) {
            int q = qb * 64 + w * 16 + rbase + j;
            O[rowbase + (size_t)q * DMODEL + dt * 16 + lr] = f2b(oac[dt][j] * rlq[j]);
        }
    }
}

extern "C" void kernel_launch(void* const* d_in, const int* in_sizes, int n_in,
                              void* d_out, int out_size, void* d_ws, size_t ws_size,
                              hipStream_t stream) {
    const float* X = (const float*)d_in[0];
    const int* vlens = (const int*)d_in[1];
    const float* Wq = (const float*)d_in[2];
    const float* Wk = (const float*)d_in[3];
    const float* Wv = (const float*)d_in[4];
    const float* Wo = (const float*)d_in[5];
    float* out = (float*)d_out;

    short* Xb = (short*)d_ws;
    short* Wqb = Xb + (size_t)MROWS * DMODEL;
    short* Wkb = Wqb + (size_t)DMODEL * DMODEL;
    short* Wvb = Wkb + (size_t)DMODEL * DMODEL;
    short* Wob = Wvb + (size_t)DMODEL * DMODEL;
    short* Qb = Wob + (size_t)DMODEL * DMODEL;
    short* Kb = Qb + (size_t)MROWS * DMODEL;
    short* Vtb = Kb + (size_t)MROWS * DMODEL;  // Vt[b][h][d][key], same size
    short* Ob = Vtb + (size_t)MROWS * DMODEL;

    cvt_kernel<<<dim3(512, 5), 256, 0, stream>>>(X, Wq, Wk, Wv, Wo, Xb, Wqb, Wkb,
                                                 Wvb, Wob);
    gemm_bt<0><<<dim3(8, 32, 3), 256, 0, stream>>>(Xb, Wqb, Wkb, Wvb, Qb, Kb, Vtb,
                                                   nullptr, MROWS, DMODEL, DMODEL);
    attn_kernel<<<dim3(1024), 256, 0, stream>>>(Qb, Kb, Vtb, Ob, vlens);
    gemm_bt<1><<<dim3(8, 32, 1), 256, 0, stream>>>(Ob, Wob, Wob, Wob, nullptr,
                                                   nullptr, nullptr, out, MROWS,
                                                   DMODEL, DMODEL);
}